// Round 2
// baseline (74.770 us; speedup 1.0000x reference)
//
#include <hip/hip_runtime.h>
#include <hip/hip_bf16.h>
#include <cstdint>

typedef __bf16 bf16_t;
typedef __bf16 bf16x8 __attribute__((ext_vector_type(8)));
typedef float f32x4 __attribute__((ext_vector_type(4)));

#define B_    2
#define S_    2048
#define HID_  768
#define NH_   12
#define HD_   64
#define KDIM_ 768

// element counts
#define N_HID_  3145728   // B*S*HID
#define N_WQKV_ 1769472   // 3*HID*HID
#define N_WO_   589824    // HID*HID

// async global->LDS, 16B per lane. LDS dest is wave-uniform base; HW writes base + lane*16.
__device__ __forceinline__ void glds16(const bf16_t* g, const bf16_t* lds) {
  __builtin_amdgcn_global_load_lds((const __attribute__((address_space(1))) void*)g,
                                   (__attribute__((address_space(3))) void*)lds,
                                   16, 0, 0);
}

// ---------------------------------------------------------------------------
// f32 -> bf16 conversion for the three operand tensors (one fused kernel).
// 8 elements per thread; all segment sizes divisible by 8.
// ---------------------------------------------------------------------------
__global__ __launch_bounds__(256) void cvt3_kernel(
    const float* __restrict__ a, const float* __restrict__ b, const float* __restrict__ c,
    bf16_t* __restrict__ da, bf16_t* __restrict__ db, bf16_t* __restrict__ dc)
{
  size_t i = ((size_t)blockIdx.x * 256 + threadIdx.x) * 8;
  const float* s; bf16_t* d; size_t off;
  if (i < N_HID_)                { s = a; d = da; off = i; }
  else if (i < N_HID_ + N_WQKV_) { s = b; d = db; off = i - N_HID_; }
  else                           { s = c; d = dc; off = i - (N_HID_ + N_WQKV_); }
  float4 v0 = *(const float4*)(s + off);
  float4 v1 = *(const float4*)(s + off + 4);
  bf16x8 o;
  o[0] = (bf16_t)v0.x; o[1] = (bf16_t)v0.y; o[2] = (bf16_t)v0.z; o[3] = (bf16_t)v0.w;
  o[4] = (bf16_t)v1.x; o[5] = (bf16_t)v1.y; o[6] = (bf16_t)v1.z; o[7] = (bf16_t)v1.w;
  *(bf16x8*)(d + off) = o;
}

// ---------------------------------------------------------------------------
// GEMM: C[M,N] = A[M,K] @ Bw[N,K]^T   (both operands K-contiguous, bf16)
// MODE 0: QKV projection, epilogue applies RoPE, scatters bf16 to Q/K/V [B,NH,S,HD]
// MODE 1: output projection, epilogue stores f32 to outf [M,HID]
// 128x128 tile, BK=64, 4 waves (2x2 of 64x64), 16x16x32 bf16 MFMA.
// LDS: [row][64] bf16 linear; 16B-slot XOR swizzle (slot ^= row&7) applied on the
// *global source* side (global_load_lds writes linearly), undone at ds_read.
// ---------------------------------------------------------------------------
template<int MODE>
__launch_bounds__(256, 2)
__global__ void gemm_kernel(const bf16_t* __restrict__ A,
                            const bf16_t* __restrict__ Bw,
                            bf16_t* __restrict__ Qo,
                            bf16_t* __restrict__ Ko,
                            bf16_t* __restrict__ Vo,
                            float* __restrict__ outf)
{
  __shared__ bf16_t As[128 * 64];
  __shared__ bf16_t Bs[128 * 64];

  const int tid  = threadIdx.x;
  const int w    = tid >> 6;
  const int lane = tid & 63;
  const int wm   = w >> 1, wn = w & 1;
  const int m0   = blockIdx.y * 128;
  const int n0   = blockIdx.x * 128;

  f32x4 acc[4][4];
#pragma unroll
  for (int i = 0; i < 4; i++)
#pragma unroll
    for (int j = 0; j < 4; j++) acc[i][j] = f32x4{0.f, 0.f, 0.f, 0.f};

  const int lr  = lane >> 3;   // row within an 8-row wave issue
  const int sub = lane & 7;    // 16B slot within 128B row

  for (int k0 = 0; k0 < KDIM_; k0 += 64) {
#pragma unroll
    for (int q = 0; q < 4; ++q) {
      const int row = q * 32 + w * 8 + lr;        // 0..127
      const int c16 = sub ^ (row & 7);            // inverse-swizzled source slot
      glds16(A  + (size_t)(m0 + row) * KDIM_ + k0 + c16 * 8, &As[(q * 32 + w * 8) * 64]);
      glds16(Bw + (size_t)(n0 + row) * KDIM_ + k0 + c16 * 8, &Bs[(q * 32 + w * 8) * 64]);
    }
    __syncthreads();

#pragma unroll
    for (int kk = 0; kk < 2; ++kk) {
      const int su = kk * 4 + (lane >> 4);        // logical 16B slot (8 bf16 of K)
      bf16x8 af[4], bfr[4];
#pragma unroll
      for (int m = 0; m < 4; m++) {
        const int row = wm * 64 + m * 16 + (lane & 15);
        af[m] = *(const bf16x8*)&As[row * 64 + (su ^ (row & 7)) * 8];
      }
#pragma unroll
      for (int n = 0; n < 4; n++) {
        const int row = wn * 64 + n * 16 + (lane & 15);
        bfr[n] = *(const bf16x8*)&Bs[row * 64 + (su ^ (row & 7)) * 8];
      }
#pragma unroll
      for (int m = 0; m < 4; m++)
#pragma unroll
        for (int n = 0; n < 4; n++)
          acc[m][n] = __builtin_amdgcn_mfma_f32_16x16x32_bf16(af[m], bfr[n], acc[m][n], 0, 0, 0);
    }
    __syncthreads();
  }

  // ----- epilogue -----
  const int c = lane & 15;
  if constexpr (MODE == 1) {
#pragma unroll
    for (int m = 0; m < 4; m++)
#pragma unroll
      for (int r = 0; r < 4; r++) {
        const int row = m0 + wm * 64 + m * 16 + (lane >> 4) * 4 + r;
#pragma unroll
        for (int nf = 0; nf < 4; nf++)
          outf[(size_t)row * HID_ + n0 + wn * 64 + nf * 16 + c] = acc[m][nf][r];
      }
  } else {
    // 64 output cols per wave == one head of one of {q,k,v}
    const int slot  = blockIdx.x * 2 + wn;        // 0..35
    const int which = slot / NH_;                 // 0=q 1=k 2=v
    const int h     = slot % NH_;
    bf16_t* dst = (which == 0) ? Qo : (which == 1 ? Ko : Vo);
    // inv_freq[i] = 10000^(-i/32) = exp2(-i * log2(10000)/32)
    const float NL = -13.287712379549449f / 32.0f;
    const float invf0 = exp2f((float)c * NL);
    const float invf1 = exp2f((float)(16 + c) * NL);
#pragma unroll
    for (int m = 0; m < 4; m++)
#pragma unroll
      for (int r = 0; r < 4; r++) {
        const int row = m0 + wm * 64 + m * 16 + (lane >> 4) * 4 + r;
        const int b = row >> 11, s = row & 2047;
        const size_t base = ((size_t)(b * NH_ + h) * S_ + s) * HD_;
        if (which == 2) {
#pragma unroll
          for (int nf = 0; nf < 4; nf++)
            dst[base + nf * 16 + c] = (bf16_t)acc[m][nf][r];
        } else {
#pragma unroll
          for (int nf = 0; nf < 2; nf++) {
            float sn, cs;
            __sincosf((float)s * (nf ? invf1 : invf0), &sn, &cs);
            const float x1 = acc[m][nf][r], x2 = acc[m][nf + 2][r];
            dst[base + nf * 16 + c]      = (bf16_t)(x1 * cs - x2 * sn);   // d
            dst[base + 32 + nf * 16 + c] = (bf16_t)(x2 * cs + x1 * sn);   // d+32
          }
        }
      }
  }
}

// ---------------------------------------------------------------------------
// Windowed attention. One 128-thread block (2 waves) per (b, h, 32 q-rows).
// Wave w owns q-rows [w*16, w*16+16); its 129-key window lives inside the
// block's 160-key staged range [bx*32-64, bx*32+96).
// K staged [160][64] via swizzled global_load_lds (rows are MFMA-B^T layout).
// V staged TRANSPOSED [64][184] so PV B-fragments are contiguous b128 reads.
// ---------------------------------------------------------------------------
__launch_bounds__(128, 2)
__global__ void attn_kernel(const bf16_t* __restrict__ Qw,
                            const bf16_t* __restrict__ Kw,
                            const bf16_t* __restrict__ Vw,
                            bf16_t* __restrict__ Ob)
{
  __shared__ bf16_t Kt[160 * 64];
  __shared__ bf16_t Vt[64 * 184];
  __shared__ bf16_t Pl[2][16 * 168];

  const int tid  = threadIdx.x;
  const int w    = tid >> 6;
  const int lane = tid & 63;
  const int bxq  = blockIdx.x;                 // 0..63
  const int h    = blockIdx.y, b = blockIdx.z;
  const size_t base = (size_t)(b * NH_ + h) * S_ * HD_;
  const int kb = bxq * 32 - 64;                // global key index of staged slot 0

  // --- stage K (swizzled source, linear LDS dest) ---
  {
    const int lr = lane >> 3, sub = lane & 7;
#pragma unroll
    for (int q = 0; q < 10; q++) {
      const int bk = q * 16 + w * 8 + lr;      // 0..159
      int j = kb + bk; j = j < 0 ? 0 : (j > S_ - 1 ? S_ - 1 : j);  // clamp; masked later
      const int c16 = sub ^ (bk & 7);
      glds16(Kw + base + (size_t)j * HD_ + c16 * 8, &Kt[(q * 16 + w * 8) * 64]);
    }
  }
  // --- stage V transposed: Vt[d][bk] ---
  {
#pragma unroll
    for (int it = 0; it < 10; ++it) {
      const int bk = it * 16 + (tid >> 3);
      const int d0 = (tid & 7) * 8;
      int j = kb + bk; j = j < 0 ? 0 : (j > S_ - 1 ? S_ - 1 : j);
      bf16x8 v = *(const bf16x8*)(Vw + base + (size_t)j * HD_ + d0);
#pragma unroll
      for (int e = 0; e < 8; e++) Vt[(d0 + e) * 184 + bk] = v[e];
    }
    // zero pad columns 160..183 (read by the zero-padded P tail, must be finite)
    for (int idx = tid; idx < 64 * 24; idx += 128) {
      const int d = idx / 24, cc = 160 + idx % 24;
      Vt[d * 184 + cc] = (bf16_t)0.0f;
    }
  }
  __syncthreads();

  // --- Q fragments straight from global (2 x b128 per lane) ---
  const int i0 = bxq * 32 + w * 16;
  bf16x8 qf[2];
#pragma unroll
  for (int kk = 0; kk < 2; kk++)
    qf[kk] = *(const bf16x8*)(Qw + base + (size_t)(i0 + (lane & 15)) * HD_ + kk * 32 + (lane >> 4) * 8);

  // --- scores: 9 key-tiles of 16, D[row=q][col=key] ---
  f32x4 sc[9];
#pragma unroll
  for (int t = 0; t < 9; t++) sc[t] = f32x4{0.f, 0.f, 0.f, 0.f};
#pragma unroll
  for (int kk = 0; kk < 2; kk++) {
    const int su = kk * 4 + (lane >> 4);
#pragma unroll
    for (int t = 0; t < 9; t++) {
      const int bk = w * 16 + t * 16 + (lane & 15);
      bf16x8 kf = *(const bf16x8*)&Kt[bk * 64 + (su ^ (bk & 7)) * 8];
      sc[t] = __builtin_amdgcn_mfma_f32_16x16x32_bf16(qf[kk], kf, sc[t], 0, 0, 0);
    }
  }

  // --- masked softmax (rows live on fixed lanes; reduce over 16-lane col groups) ---
  const int c  = lane & 15;
  const int qh = lane >> 4;
  float lrow[4];
#pragma unroll
  for (int r = 0; r < 4; r++) {
    const int i = i0 + qh * 4 + r;
    float mx = -1e30f;
#pragma unroll
    for (int t = 0; t < 9; t++) {
      const int j = kb + w * 16 + t * 16 + c;
      const int dd = j - i;
      const bool valid = (dd >= -64) && (dd <= 64) && (j >= 0) && (j < S_);
      const float v = valid ? sc[t][r] * 0.125f : -1e30f;
      sc[t][r] = v;
      mx = fmaxf(mx, v);
    }
    mx = fmaxf(mx, __shfl_xor(mx, 1, 16));
    mx = fmaxf(mx, __shfl_xor(mx, 2, 16));
    mx = fmaxf(mx, __shfl_xor(mx, 4, 16));
    mx = fmaxf(mx, __shfl_xor(mx, 8, 16));
    float sum = 0.f;
#pragma unroll
    for (int t = 0; t < 9; t++) {
      const float p = __expf(sc[t][r] - mx);
      sc[t][r] = p;
      sum += p;
    }
    sum += __shfl_xor(sum, 1, 16);
    sum += __shfl_xor(sum, 2, 16);
    sum += __shfl_xor(sum, 4, 16);
    sum += __shfl_xor(sum, 8, 16);
    lrow[r] = sum;
  }

  // --- P -> LDS (per-wave private), zero-pad key cols 144..159 ---
#pragma unroll
  for (int t = 0; t < 9; t++)
#pragma unroll
    for (int r = 0; r < 4; r++)
      Pl[w][(qh * 4 + r) * 168 + t * 16 + c] = (bf16_t)sc[t][r];
#pragma unroll
  for (int r = 0; r < 4; r++)
    Pl[w][(qh * 4 + r) * 168 + 144 + c] = (bf16_t)0.0f;
  asm volatile("s_waitcnt lgkmcnt(0)" ::: "memory");
  __builtin_amdgcn_sched_barrier(0);

  // --- PV: A=P[16 x 160], B=Vt ---
  f32x4 ao[4];
#pragma unroll
  for (int nf = 0; nf < 4; nf++) ao[nf] = f32x4{0.f, 0.f, 0.f, 0.f};
#pragma unroll
  for (int kc = 0; kc < 5; kc++) {
    bf16x8 pf = *(const bf16x8*)&Pl[w][(lane & 15) * 168 + kc * 32 + (lane >> 4) * 8];
#pragma unroll
    for (int nf = 0; nf < 4; nf++) {
      const int d = nf * 16 + (lane & 15);
      bf16x8 vf = *(const bf16x8*)&Vt[d * 184 + w * 16 + kc * 32 + (lane >> 4) * 8];
      ao[nf] = __builtin_amdgcn_mfma_f32_16x16x32_bf16(pf, vf, ao[nf], 0, 0, 0);
    }
  }

  // --- normalize + store to attn buffer [b][s][h*64+d] ---
#pragma unroll
  for (int r = 0; r < 4; r++) {
    const float inv = 1.0f / lrow[r];
    const int srow = i0 + qh * 4 + r;
    const size_t orow = ((size_t)(b * S_ + srow)) * HID_ + h * HD_;
#pragma unroll
    for (int nf = 0; nf < 4; nf++)
      Ob[orow + nf * 16 + c] = (bf16_t)(ao[nf][r] * inv);
  }
}

// ---------------------------------------------------------------------------
extern "C" void kernel_launch(void* const* d_in, const int* in_sizes, int n_in,
                              void* d_out, int out_size, void* d_ws, size_t ws_size,
                              hipStream_t stream) {
  const float* hidden_f = (const float*)d_in[0];
  const float* wqkv_f   = (const float*)d_in[1];
  const float* wo_f     = (const float*)d_in[2];
  // d_in[3] (band mask) and d_in[4] (position_ids=arange) are deterministic; computed analytically.

  bf16_t* ws = (bf16_t*)d_ws;
  size_t off = 0;
  bf16_t* Hb    = ws + off; off += N_HID_;     // bf16 hidden
  bf16_t* Wqkvb = ws + off; off += N_WQKV_;    // bf16 Wqkv
  bf16_t* Wob   = ws + off; off += N_WO_;      // bf16 Wo
  const size_t E = (size_t)B_ * NH_ * S_ * HD_;
  bf16_t* Q    = ws + off; off += E;
  bf16_t* K    = ws + off; off += E;
  bf16_t* V    = ws + off; off += E;
  bf16_t* ABUF = ws + off; off += E;           // [B*S, 768] attention output (bf16)
  float*  out  = (float*)d_out;

  // 0) convert f32 inputs -> bf16 workspace copies
  cvt3_kernel<<<dim3((N_HID_ + N_WQKV_ + N_WO_) / (256 * 8)), dim3(256), 0, stream>>>(
      hidden_f, wqkv_f, wo_f, Hb, Wqkvb, Wob);
  // 1) QKV projection + RoPE -> Q,K,V [B,NH,S,HD]
  gemm_kernel<0><<<dim3(18, 32), dim3(256), 0, stream>>>(Hb, Wqkvb, Q, K, V, nullptr);
  // 2) sliding-window attention -> ABUF [B*S, 768]
  attn_kernel<<<dim3(64, 12, 2), dim3(128), 0, stream>>>(Q, K, V, ABUF);
  // 3) output projection -> f32 out
  gemm_kernel<1><<<dim3(6, 32), dim3(256), 0, stream>>>(ABUF, Wob, nullptr, nullptr, nullptr, out);
}

// Round 3
// 68.984 us; speedup vs baseline: 1.0839x; 1.0839x over previous
//
#include <hip/hip_runtime.h>
#include <hip/hip_bf16.h>
#include <cstdint>

typedef __bf16 bf16_t;
typedef __bf16 bf16x8 __attribute__((ext_vector_type(8)));
typedef float f32x4 __attribute__((ext_vector_type(4)));

#define B_    2
#define S_    2048
#define HID_  768
#define NH_   12
#define HD_   64
#define KDIM_ 768

// element counts
#define N_HID_  3145728   // B*S*HID
#define N_WQKV_ 1769472   // 3*HID*HID
#define N_WO_   589824    // HID*HID

// async global->LDS, 16B per lane. LDS dest is wave-uniform base; HW writes base + lane*16.
__device__ __forceinline__ void glds16(const bf16_t* g, const bf16_t* lds) {
  __builtin_amdgcn_global_load_lds((const __attribute__((address_space(1))) void*)g,
                                   (__attribute__((address_space(3))) void*)lds,
                                   16, 0, 0);
}

// ---------------------------------------------------------------------------
// f32 -> bf16 conversion for the three operand tensors (one fused kernel).
// ---------------------------------------------------------------------------
__global__ __launch_bounds__(256) void cvt3_kernel(
    const float* __restrict__ a, const float* __restrict__ b, const float* __restrict__ c,
    bf16_t* __restrict__ da, bf16_t* __restrict__ db, bf16_t* __restrict__ dc)
{
  size_t i = ((size_t)blockIdx.x * 256 + threadIdx.x) * 8;
  const float* s; bf16_t* d; size_t off;
  if (i < N_HID_)                { s = a; d = da; off = i; }
  else if (i < N_HID_ + N_WQKV_) { s = b; d = db; off = i - N_HID_; }
  else                           { s = c; d = dc; off = i - (N_HID_ + N_WQKV_); }
  float4 v0 = *(const float4*)(s + off);
  float4 v1 = *(const float4*)(s + off + 4);
  bf16x8 o;
  o[0] = (bf16_t)v0.x; o[1] = (bf16_t)v0.y; o[2] = (bf16_t)v0.z; o[3] = (bf16_t)v0.w;
  o[4] = (bf16_t)v1.x; o[5] = (bf16_t)v1.y; o[6] = (bf16_t)v1.z; o[7] = (bf16_t)v1.w;
  *(bf16x8*)(d + off) = o;
}

// ---------------------------------------------------------------------------
// GEMM: C[M,N] = A[M,K] @ Bw[N,K]^T   (both operands K-contiguous, bf16)
// MODE 0 (BN=128): QKV projection; epilogue applies RoPE, scatters bf16 Q/K/V.
// MODE 1 (BN=64):  output projection; epilogue stores f32. 384 blocks.
// 128xBN tile, BK=64, 4 waves (2x2), 16x16x32 bf16 MFMA.
// LDS: [row][64] bf16 linear; 16B-slot XOR swizzle (slot ^= row&7) applied on
// the *global source* side (global_load_lds writes linearly), undone at ds_read.
// ---------------------------------------------------------------------------
template<int MODE, int BN>
__launch_bounds__(256, 2)
__global__ void gemm_kernel(const bf16_t* __restrict__ A,
                            const bf16_t* __restrict__ Bw,
                            bf16_t* __restrict__ Qo,
                            bf16_t* __restrict__ Ko,
                            bf16_t* __restrict__ Vo,
                            float* __restrict__ outf)
{
  constexpr int NWF = BN / 32;          // per-wave N fragments; also B-stage issues
  __shared__ bf16_t As[128 * 64];
  __shared__ bf16_t Bs[BN * 64];

  const int tid  = threadIdx.x;
  const int w    = tid >> 6;
  const int lane = tid & 63;
  const int wm   = w >> 1, wn = w & 1;
  const int m0   = blockIdx.y * 128;
  const int n0   = blockIdx.x * BN;

  f32x4 acc[4][NWF];
#pragma unroll
  for (int i = 0; i < 4; i++)
#pragma unroll
    for (int j = 0; j < NWF; j++) acc[i][j] = f32x4{0.f, 0.f, 0.f, 0.f};

  const int lr  = lane >> 3;   // row within an 8-row wave issue
  const int sub = lane & 7;    // 16B slot within 128B row

  for (int k0 = 0; k0 < KDIM_; k0 += 64) {
#pragma unroll
    for (int q = 0; q < 4; ++q) {
      const int row = q * 32 + w * 8 + lr;        // 0..127
      const int c16 = sub ^ (row & 7);            // inverse-swizzled source slot
      glds16(A + (size_t)(m0 + row) * KDIM_ + k0 + c16 * 8, &As[(q * 32 + w * 8) * 64]);
    }
#pragma unroll
    for (int q = 0; q < NWF; ++q) {
      const int row = q * 32 + w * 8 + lr;        // 0..BN-1
      const int c16 = sub ^ (row & 7);
      glds16(Bw + (size_t)(n0 + row) * KDIM_ + k0 + c16 * 8, &Bs[(q * 32 + w * 8) * 64]);
    }
    __syncthreads();

#pragma unroll
    for (int kk = 0; kk < 2; ++kk) {
      const int su = kk * 4 + (lane >> 4);        // logical 16B slot (8 bf16 of K)
      bf16x8 af[4], bfr[NWF];
#pragma unroll
      for (int m = 0; m < 4; m++) {
        const int row = wm * 64 + m * 16 + (lane & 15);
        af[m] = *(const bf16x8*)&As[row * 64 + (su ^ (row & 7)) * 8];
      }
#pragma unroll
      for (int n = 0; n < NWF; n++) {
        const int row = wn * (BN / 2) + n * 16 + (lane & 15);
        bfr[n] = *(const bf16x8*)&Bs[row * 64 + (su ^ (row & 7)) * 8];
      }
#pragma unroll
      for (int m = 0; m < 4; m++)
#pragma unroll
        for (int n = 0; n < NWF; n++)
          acc[m][n] = __builtin_amdgcn_mfma_f32_16x16x32_bf16(af[m], bfr[n], acc[m][n], 0, 0, 0);
    }
    __syncthreads();
  }

  // ----- epilogue -----
  const int c = lane & 15;
  if constexpr (MODE == 1) {
#pragma unroll
    for (int m = 0; m < 4; m++)
#pragma unroll
      for (int r = 0; r < 4; r++) {
        const int row = m0 + wm * 64 + m * 16 + (lane >> 4) * 4 + r;
#pragma unroll
        for (int nf = 0; nf < NWF; nf++)
          outf[(size_t)row * HID_ + n0 + wn * (BN / 2) + nf * 16 + c] = acc[m][nf][r];
      }
  } else {
    // 64 output cols per wave == one head of one of {q,k,v}  (BN=128 only)
    const int slot  = blockIdx.x * 2 + wn;        // 0..35
    const int which = slot / NH_;                 // 0=q 1=k 2=v
    const int h     = slot % NH_;
    bf16_t* dst = (which == 0) ? Qo : (which == 1 ? Ko : Vo);
    // inv_freq[i] = 10000^(-i/32) = exp2(-i * log2(10000)/32)
    const float NL = -13.287712379549449f / 32.0f;
    const float invf0 = exp2f((float)c * NL);
    const float invf1 = exp2f((float)(16 + c) * NL);
#pragma unroll
    for (int m = 0; m < 4; m++)
#pragma unroll
      for (int r = 0; r < 4; r++) {
        const int row = m0 + wm * 64 + m * 16 + (lane >> 4) * 4 + r;
        const int b = row >> 11, s = row & 2047;
        const size_t base = ((size_t)(b * NH_ + h) * S_ + s) * HD_;
        if (which == 2) {
#pragma unroll
          for (int nf = 0; nf < 4; nf++)
            dst[base + nf * 16 + c] = (bf16_t)acc[m][nf][r];
        } else {
#pragma unroll
          for (int nf = 0; nf < 2; nf++) {
            float sn, cs;
            __sincosf((float)s * (nf ? invf1 : invf0), &sn, &cs);
            const float x1 = acc[m][nf][r], x2 = acc[m][nf + 2][r];
            dst[base + nf * 16 + c]      = (bf16_t)(x1 * cs - x2 * sn);   // d
            dst[base + 32 + nf * 16 + c] = (bf16_t)(x2 * cs + x1 * sn);   // d+32
          }
        }
      }
  }
}

// ---------------------------------------------------------------------------
// Windowed attention. One 128-thread block (2 waves) per (b, h, 32 q-rows).
// Wave w owns q-rows [w*16, w*16+16); its 129-key window lives inside the
// block's 160-key range [bx*32-64, bx*32+96).
// K fragments read DIRECT from global (each element used once per wave; rows
// are contiguous bf16x8 — L1/L2-resident, LDS staging was pure overhead).
// V staged TRANSPOSED [64][184] so PV B-fragments are contiguous b128 reads.
// LDS = 34.3 KB -> 4 blocks/CU.
// ---------------------------------------------------------------------------
__launch_bounds__(128, 4)
__global__ void attn_kernel(const bf16_t* __restrict__ Qw,
                            const bf16_t* __restrict__ Kw,
                            const bf16_t* __restrict__ Vw,
                            bf16_t* __restrict__ Ob)
{
  __shared__ bf16_t Vt[64 * 184];
  __shared__ bf16_t Pl[2][16 * 168];

  const int tid  = threadIdx.x;
  const int w    = tid >> 6;
  const int lane = tid & 63;
  const int bxq  = blockIdx.x;                 // 0..63
  const int h    = blockIdx.y, b = blockIdx.z;
  const size_t base = (size_t)(b * NH_ + h) * S_ * HD_;
  const int kb = bxq * 32 - 64;                // global key index of staged slot 0

  // --- Q fragments straight from global (2 x b128 per lane) ---
  const int i0 = bxq * 32 + w * 16;
  bf16x8 qf[2];
#pragma unroll
  for (int kk = 0; kk < 2; kk++)
    qf[kk] = *(const bf16x8*)(Qw + base + (size_t)(i0 + (lane & 15)) * HD_ + kk * 32 + (lane >> 4) * 8);

  // --- stage V transposed: Vt[d][bk] ---
  {
#pragma unroll
    for (int it = 0; it < 10; ++it) {
      const int bk = it * 16 + (tid >> 3);
      const int d0 = (tid & 7) * 8;
      int j = kb + bk; j = j < 0 ? 0 : (j > S_ - 1 ? S_ - 1 : j);
      bf16x8 v = *(const bf16x8*)(Vw + base + (size_t)j * HD_ + d0);
#pragma unroll
      for (int e = 0; e < 8; e++) Vt[(d0 + e) * 184 + bk] = v[e];
    }
    // zero pad columns 160..183 (read by the zero-padded P tail, must be finite)
    for (int idx = tid; idx < 64 * 24; idx += 128) {
      const int d = idx / 24, cc = 160 + idx % 24;
      Vt[d * 184 + cc] = (bf16_t)0.0f;
    }
  }
  __syncthreads();

  // --- scores: 9 key-tiles of 16, D[row=q][col=key]; K direct from global ---
  f32x4 sc[9];
#pragma unroll
  for (int t = 0; t < 9; t++) sc[t] = f32x4{0.f, 0.f, 0.f, 0.f};
#pragma unroll
  for (int kk = 0; kk < 2; kk++) {
    const int su = kk * 4 + (lane >> 4);
#pragma unroll
    for (int t = 0; t < 9; t++) {
      const int bk = w * 16 + t * 16 + (lane & 15);
      int j = kb + bk; j = j < 0 ? 0 : (j > S_ - 1 ? S_ - 1 : j);  // clamp; masked below
      bf16x8 kf = *(const bf16x8*)(Kw + base + (size_t)j * HD_ + su * 8);
      sc[t] = __builtin_amdgcn_mfma_f32_16x16x32_bf16(qf[kk], kf, sc[t], 0, 0, 0);
    }
  }

  // --- masked softmax (rows live on fixed lanes; reduce over 16-lane col groups) ---
  const int c  = lane & 15;
  const int qh = lane >> 4;
  float lrow[4];
#pragma unroll
  for (int r = 0; r < 4; r++) {
    const int i = i0 + qh * 4 + r;
    float mx = -1e30f;
#pragma unroll
    for (int t = 0; t < 9; t++) {
      const int j = kb + w * 16 + t * 16 + c;
      const int dd = j - i;
      const bool valid = (dd >= -64) && (dd <= 64) && (j >= 0) && (j < S_);
      const float v = valid ? sc[t][r] * 0.125f : -1e30f;
      sc[t][r] = v;
      mx = fmaxf(mx, v);
    }
    mx = fmaxf(mx, __shfl_xor(mx, 1, 16));
    mx = fmaxf(mx, __shfl_xor(mx, 2, 16));
    mx = fmaxf(mx, __shfl_xor(mx, 4, 16));
    mx = fmaxf(mx, __shfl_xor(mx, 8, 16));
    float sum = 0.f;
#pragma unroll
    for (int t = 0; t < 9; t++) {
      const float p = __expf(sc[t][r] - mx);
      sc[t][r] = p;
      sum += p;
    }
    sum += __shfl_xor(sum, 1, 16);
    sum += __shfl_xor(sum, 2, 16);
    sum += __shfl_xor(sum, 4, 16);
    sum += __shfl_xor(sum, 8, 16);
    lrow[r] = sum;
  }

  // --- P -> LDS (per-wave private), zero-pad key cols 144..159 ---
#pragma unroll
  for (int t = 0; t < 9; t++)
#pragma unroll
    for (int r = 0; r < 4; r++)
      Pl[w][(qh * 4 + r) * 168 + t * 16 + c] = (bf16_t)sc[t][r];
#pragma unroll
  for (int r = 0; r < 4; r++)
    Pl[w][(qh * 4 + r) * 168 + 144 + c] = (bf16_t)0.0f;
  asm volatile("s_waitcnt lgkmcnt(0)" ::: "memory");
  __builtin_amdgcn_sched_barrier(0);

  // --- PV: A=P[16 x 160], B=Vt ---
  f32x4 ao[4];
#pragma unroll
  for (int nf = 0; nf < 4; nf++) ao[nf] = f32x4{0.f, 0.f, 0.f, 0.f};
#pragma unroll
  for (int kc = 0; kc < 5; kc++) {
    bf16x8 pf = *(const bf16x8*)&Pl[w][(lane & 15) * 168 + kc * 32 + (lane >> 4) * 8];
#pragma unroll
    for (int nf = 0; nf < 4; nf++) {
      const int d = nf * 16 + (lane & 15);
      bf16x8 vf = *(const bf16x8*)&Vt[d * 184 + w * 16 + kc * 32 + (lane >> 4) * 8];
      ao[nf] = __builtin_amdgcn_mfma_f32_16x16x32_bf16(pf, vf, ao[nf], 0, 0, 0);
    }
  }

  // --- normalize + store to attn buffer [b][s][h*64+d] ---
#pragma unroll
  for (int r = 0; r < 4; r++) {
    const float inv = 1.0f / lrow[r];
    const int srow = i0 + qh * 4 + r;
    const size_t orow = ((size_t)(b * S_ + srow)) * HID_ + h * HD_;
#pragma unroll
    for (int nf = 0; nf < 4; nf++)
      Ob[orow + nf * 16 + c] = (bf16_t)(ao[nf][r] * inv);
  }
}

// ---------------------------------------------------------------------------
extern "C" void kernel_launch(void* const* d_in, const int* in_sizes, int n_in,
                              void* d_out, int out_size, void* d_ws, size_t ws_size,
                              hipStream_t stream) {
  const float* hidden_f = (const float*)d_in[0];
  const float* wqkv_f   = (const float*)d_in[1];
  const float* wo_f     = (const float*)d_in[2];
  // d_in[3] (band mask) and d_in[4] (position_ids=arange) are deterministic; computed analytically.

  bf16_t* ws = (bf16_t*)d_ws;
  size_t off = 0;
  bf16_t* Hb    = ws + off; off += N_HID_;     // bf16 hidden
  bf16_t* Wqkvb = ws + off; off += N_WQKV_;    // bf16 Wqkv
  bf16_t* Wob   = ws + off; off += N_WO_;      // bf16 Wo
  const size_t E = (size_t)B_ * NH_ * S_ * HD_;
  bf16_t* Q    = ws + off; off += E;
  bf16_t* K    = ws + off; off += E;
  bf16_t* V    = ws + off; off += E;
  bf16_t* ABUF = ws + off; off += E;           // [B*S, 768] attention output (bf16)
  float*  out  = (float*)d_out;

  // 0) convert f32 inputs -> bf16 workspace copies
  cvt3_kernel<<<dim3((N_HID_ + N_WQKV_ + N_WO_) / (256 * 8)), dim3(256), 0, stream>>>(
      hidden_f, wqkv_f, wo_f, Hb, Wqkvb, Wob);
  // 1) QKV projection + RoPE -> Q,K,V [B,NH,S,HD]
  gemm_kernel<0, 128><<<dim3(18, 32), dim3(256), 0, stream>>>(Hb, Wqkvb, Q, K, V, nullptr);
  // 2) sliding-window attention -> ABUF [B*S, 768]
  attn_kernel<<<dim3(64, 12, 2), dim3(128), 0, stream>>>(Q, K, V, ABUF);
  // 3) output projection (128x64 tiles, 384 blocks) -> f32 out
  gemm_kernel<1, 64><<<dim3(12, 32), dim3(256), 0, stream>>>(ABUF, Wob, nullptr, nullptr, nullptr, out);
}